// Round 4
// baseline (230.448 us; speedup 1.0000x reference)
//
#include <hip/hip_runtime.h>
#include <hip/hip_bf16.h>

// Problem: B=8, S=1024, EMBED=1024, DK=DV=512, M=64. Inputs/outputs f32.
// Identity: landmark selection is a segment permutation P of k, so
// kernel_1 = K3 P^T, pinv(kernel_2) = P pinv(K3), and
// out = K3 K3+ K3 v = K3 v == softmax(q k^T) v  (standard attention).
#define SS   1024
#define DKK  512

typedef __hip_bfloat16 bf16;
typedef __attribute__((ext_vector_type(8))) short s16x8;            // 8 x bf16
typedef __attribute__((ext_vector_type(8))) unsigned short u16x8;
typedef __attribute__((ext_vector_type(4))) float f32x4;

// ---- ws layout (byte offsets), 76 MiB ----
// W(z) bf16 1 MiB at 48+z MiB; q 52 MiB; k 60 MiB; vT 68 MiB; logits 16 MiB at 0.
#define WS_W(z)  ((48ull << 20) + ((size_t)(z) << 20))
#define WS_Q     (52ull << 20)
#define WS_K     (60ull << 20)
#define WS_VT    (68ull << 20)
#define WS_LG    (0ull)

__device__ __forceinline__ void async_ld16(const void* g, void* s) {
  __builtin_amdgcn_global_load_lds(
      (const __attribute__((address_space(1))) void*)g,
      (__attribute__((address_space(3))) void*)s, 16, 0, 0);
}

__device__ __forceinline__ unsigned short f2bfu(float f) {
  return __builtin_bit_cast(unsigned short, __float2bfloat16(f));
}
__device__ __forceinline__ float bfu2f(unsigned short u) {
  unsigned int i = ((unsigned int)u) << 16;
  return __builtin_bit_cast(float, i);
}

// Convert the 3 weight tensors (512K elems each) f32 -> bf16 into ws.
__global__ __launch_bounds__(256)
void convert_w(const float* __restrict__ w0, const float* __restrict__ w1,
               const float* __restrict__ w2, char* __restrict__ ws)
{
  const int bx = blockIdx.x;
  const int z = bx >> 8, local = bx & 255;
  const float* src = (z == 0) ? w0 : (z == 1) ? w1 : w2;
  unsigned short* dst = (unsigned short*)(ws + WS_W(z));
  const int i = local * 2048 + threadIdx.x * 8;
  const float4* s = (const float4*)(src + i);
  float4 a = s[0], b = s[1];
  ushort4 o0, o1;
  o0.x = f2bfu(a.x); o0.y = f2bfu(a.y); o0.z = f2bfu(a.z); o0.w = f2bfu(a.w);
  o1.x = f2bfu(b.x); o1.y = f2bfu(b.y); o1.z = f2bfu(b.z); o1.w = f2bfu(b.w);
  ((ushort4*)(dst + i))[0] = o0;
  ((ushort4*)(dst + i))[1] = o1;
}

// ---------- bf16 x bf16 core (scores / pv) ----------
// C[BM x 128] = A[BM x K] * B[128 x K]^T, both K-contiguous bf16.
// LDS via global_load_lds w=16; LDS[row][slot] holds chunk (slot ^ (row&7)).
template<int BM, int K, int LDA, int LDB>
__device__ __forceinline__ void gemm_core(const bf16* __restrict__ A,
                                          const bf16* __restrict__ Bw,
                                          int bm, int bn,
                                          short* As, short* Bs, f32x4* acc)
{
  constexpr int MI = BM / 32;
  constexpr int AR = BM / 4;
  const int tid  = threadIdx.x;
  const int lane = tid & 63;
  const int wave = tid >> 6;
  const int l8   = lane >> 3;
  const int kch  = ((lane & 7) ^ l8) * 8;
  const bf16* ag = A  + (size_t)(bm * BM + wave * AR + l8) * LDA + kch;
  const bf16* bg = Bw + (size_t)(bn * 128 + wave * 32 + l8) * LDB + kch;
  short* AsW = As + wave * AR * 64;
  short* BsW = Bs + wave * 32 * 64;
  const int waveM = wave >> 1, waveN = wave & 1;
  const int l16  = lane & 15;
  const int quad = lane >> 4;
  const int xr   = l16 & 7;

  #pragma unroll
  for (int t = 0; t < MI * 4; ++t)
    #pragma unroll
    for (int r = 0; r < 4; ++r) acc[t][r] = 0.0f;

  for (int kt = 0; kt < K / 64; ++kt) {
    #pragma unroll
    for (int j = 0; j < AR / 8; ++j) async_ld16(ag + (size_t)j * 8 * LDA, AsW + j * 8 * 64);
    #pragma unroll
    for (int j = 0; j < 4; ++j)      async_ld16(bg + (size_t)j * 8 * LDB, BsW + j * 8 * 64);
    ag += 64; bg += 64;
    __syncthreads();
    #pragma unroll
    for (int ks = 0; ks < 2; ++ks) {
      s16x8 af[MI], bfv[4];
      #pragma unroll
      for (int mi = 0; mi < MI; ++mi) {
        const int row  = waveM * (BM / 2) + mi * 16 + l16;
        const int slot = (ks * 4 + quad) ^ xr;
        af[mi] = *(const s16x8*)&As[row * 64 + slot * 8];
      }
      #pragma unroll
      for (int ni = 0; ni < 4; ++ni) {
        const int row  = waveN * 64 + ni * 16 + l16;
        const int slot = (ks * 4 + quad) ^ xr;
        bfv[ni] = *(const s16x8*)&Bs[row * 64 + slot * 8];
      }
      #pragma unroll
      for (int mi = 0; mi < MI; ++mi)
        #pragma unroll
        for (int ni = 0; ni < 4; ++ni)
          acc[mi * 4 + ni] = __builtin_amdgcn_mfma_f32_16x16x32_bf16(
              af[mi], bfv[ni], acc[mi * 4 + ni], 0, 0, 0);
    }
    __syncthreads();
  }
}

// ---------- f32-A x bf16-B core (proj; BM=128) ----------
// A is f32 in global; staged via reg round-trip with inline f32->bf16
// conversion into the SAME swizzled LDS layout. B stays on the async path.
template<int K, int LDA, int LDB>
__device__ __forceinline__ void gemm_core_f32a(const float* __restrict__ A,
                                               const bf16* __restrict__ Bw,
                                               int bm, int bn,
                                               short* As, short* Bs, f32x4* acc)
{
  const int tid  = threadIdx.x;
  const int lane = tid & 63;
  const int wave = tid >> 6;
  const int l8   = lane >> 3;
  const int kch  = ((lane & 7) ^ l8) * 8;
  const bf16* bg = Bw + (size_t)(bn * 128 + wave * 32 + l8) * LDB + kch;
  short* BsW = Bs + wave * 32 * 64;
  // A staging: pass p covers rows p*32 + (tid>>3); chunk g = tid&7.
  // 8 lanes x 32 B contiguous per row -> 256 B coalesced segments.
  const int arow = tid >> 3;            // 0..31
  const int ag8  = tid & 7;             // k-chunk index
  const int slotA = (ag8 ^ (arow & 7)) * 8;   // p*32 keeps row&7 invariant
  const float* ag = A + (size_t)(bm * 128 + arow) * LDA + ag8 * 8;
  const int waveM = wave >> 1, waveN = wave & 1;
  const int l16  = lane & 15;
  const int quad = lane >> 4;
  const int xr   = l16 & 7;

  #pragma unroll
  for (int t = 0; t < 16; ++t)
    #pragma unroll
    for (int r = 0; r < 4; ++r) acc[t][r] = 0.0f;

  for (int kt = 0; kt < K / 64; ++kt) {
    #pragma unroll
    for (int j = 0; j < 4; ++j) async_ld16(bg + (size_t)j * 8 * LDB, BsW + j * 8 * 64);
    bg += 64;
    #pragma unroll
    for (int p = 0; p < 4; ++p) {
      const float4* s = (const float4*)(ag + (size_t)p * 32 * LDA);
      float4 a = s[0], b = s[1];
      u16x8 v;
      v[0] = f2bfu(a.x); v[1] = f2bfu(a.y); v[2] = f2bfu(a.z); v[3] = f2bfu(a.w);
      v[4] = f2bfu(b.x); v[5] = f2bfu(b.y); v[6] = f2bfu(b.z); v[7] = f2bfu(b.w);
      *(u16x8*)&As[(p * 32 + arow) * 64 + slotA] = v;
    }
    ag += 64;
    __syncthreads();
    #pragma unroll
    for (int ks = 0; ks < 2; ++ks) {
      s16x8 af[4], bfv[4];
      #pragma unroll
      for (int mi = 0; mi < 4; ++mi) {
        const int row  = waveM * 64 + mi * 16 + l16;
        const int slot = (ks * 4 + quad) ^ xr;
        af[mi] = *(const s16x8*)&As[row * 64 + slot * 8];
      }
      #pragma unroll
      for (int ni = 0; ni < 4; ++ni) {
        const int row  = waveN * 64 + ni * 16 + l16;
        const int slot = (ks * 4 + quad) ^ xr;
        bfv[ni] = *(const s16x8*)&Bs[row * 64 + slot * 8];
      }
      #pragma unroll
      for (int mi = 0; mi < 4; ++mi)
        #pragma unroll
        for (int ni = 0; ni < 4; ++ni)
          acc[mi * 4 + ni] = __builtin_amdgcn_mfma_f32_16x16x32_bf16(
              af[mi], bfv[ni], acc[mi * 4 + ni], 0, 0, 0);
    }
    __syncthreads();
  }
}

// z=0: q = (Xq Wq^T + bq) * 512^-0.5 ; z=1: k = Xk Wk^T + bk ;
// z=2: vT[b][d][s] = (Xv Wv^T + bv)^T  (so PV is also a BT-GEMM)
// grid (bn=4, bm=64, z=3): bn-fastest so same-A blocks are adjacent.
__global__ __launch_bounds__(256, 2)
void proj_kernel(const float* __restrict__ Xq, const float* __restrict__ Xk,
                 const float* __restrict__ Xv, const bf16* __restrict__ W0,
                 const float* __restrict__ bq, const float* __restrict__ bk,
                 const float* __restrict__ bv,
                 bf16* __restrict__ qo, bf16* __restrict__ ko,
                 bf16* __restrict__ vT, float qscale)
{
  __shared__ __align__(16) short As[128 * 64];
  __shared__ __align__(16) short Bs[128 * 64];
  const int z  = blockIdx.z;
  const int bn = blockIdx.x, bm = blockIdx.y;
  const float* A  = (z == 0) ? Xq : (z == 1) ? Xk : Xv;
  const bf16*  Bw = W0 + ((size_t)z << 19);
  const float* bias = (z == 0) ? bq : (z == 1) ? bk : bv;
  f32x4 acc[16];
  gemm_core_f32a<1024, 1024, 1024>(A, Bw, bm, bn, As, Bs, acc);

  const int lane = threadIdx.x & 63;
  const int wave = threadIdx.x >> 6;
  const int waveM = wave >> 1, waveN = wave & 1;
  const int l16 = lane & 15, quad = lane >> 4;
  const int row0 = bm * 128 + waveM * 64;
  const int col0 = bn * 128 + waveN * 64;
  const float sc = (z == 0) ? qscale : 1.0f;
  bf16* C = (z == 0) ? qo : ko;
  #pragma unroll
  for (int ni = 0; ni < 4; ++ni) {
    const int col = col0 + ni * 16 + l16;
    const float bb = bias[col];
    #pragma unroll
    for (int mi = 0; mi < 4; ++mi)
      #pragma unroll
      for (int r = 0; r < 4; ++r) {
        const int row = row0 + mi * 16 + quad * 4 + r;
        const float v = acc[mi * 4 + ni][r] + bb;
        if (z == 2)
          vT[((size_t)(row >> 10) * DKK + col) * SS + (row & (SS - 1))] =
              __float2bfloat16(v);
        else
          C[(size_t)row * DKK + col] = __float2bfloat16(v * sc);
      }
  }
}

// logits[b][s][t] = q[b][s].k[b][t]; BM=64 tiles. grid (bn=8, bm=16, z=8).
__global__ __launch_bounds__(256, 4)
void scores_kernel(const bf16* __restrict__ q, const bf16* __restrict__ k,
                   bf16* __restrict__ lgB)
{
  __shared__ __align__(16) short As[64 * 64];
  __shared__ __align__(16) short Bs[128 * 64];
  const int z = blockIdx.z;
  const int bn = blockIdx.x, bm = blockIdx.y;
  f32x4 acc[8];
  gemm_core<64, 512, 512, 512>(q + (size_t)z * SS * DKK, k + (size_t)z * SS * DKK,
                               bm, bn, As, Bs, acc);

  const int lane = threadIdx.x & 63;
  const int wave = threadIdx.x >> 6;
  const int waveM = wave >> 1, waveN = wave & 1;
  const int l16 = lane & 15, quad = lane >> 4;
  const int row0 = bm * 64 + waveM * 32;
  const int col0 = bn * 128 + waveN * 64;
  bf16* C = lgB + (size_t)z * SS * SS;
  #pragma unroll
  for (int ni = 0; ni < 4; ++ni) {
    const int col = col0 + ni * 16 + l16;
    #pragma unroll
    for (int mi = 0; mi < 2; ++mi)
      #pragma unroll
      for (int r = 0; r < 4; ++r) {
        const int row = row0 + mi * 16 + quad * 4 + r;
        C[(size_t)row * SS + col] = __float2bfloat16(acc[mi * 4 + ni][r]);
      }
  }
}

// In-place row softmax; one wave per 1024-wide bf16 row.
__global__ __launch_bounds__(256)
void softmax_kernel(unsigned short* __restrict__ Pm)
{
  const int lane = threadIdx.x & 63;
  const int wv   = threadIdx.x >> 6;
  const size_t row = (size_t)blockIdx.x * 4 + wv;
  ushort4* ptr = (ushort4*)(Pm + row * SS);
  ushort4 u[4];
  float x[16];
  #pragma unroll
  for (int i = 0; i < 4; ++i) u[i] = ptr[lane + i * 64];
  #pragma unroll
  for (int i = 0; i < 4; ++i) {
    x[i * 4 + 0] = bfu2f(u[i].x); x[i * 4 + 1] = bfu2f(u[i].y);
    x[i * 4 + 2] = bfu2f(u[i].z); x[i * 4 + 3] = bfu2f(u[i].w);
  }
  float m = x[0];
  #pragma unroll
  for (int i = 1; i < 16; ++i) m = fmaxf(m, x[i]);
  #pragma unroll
  for (int off = 32; off > 0; off >>= 1) m = fmaxf(m, __shfl_xor(m, off));
  float s = 0.f;
  #pragma unroll
  for (int i = 0; i < 16; ++i) { x[i] = __expf(x[i] - m); s += x[i]; }
  #pragma unroll
  for (int off = 32; off > 0; off >>= 1) s += __shfl_xor(s, off);
  const float rs = 1.0f / s;
  #pragma unroll
  for (int i = 0; i < 4; ++i) {
    ushort4 o;
    o.x = f2bfu(x[i * 4 + 0] * rs); o.y = f2bfu(x[i * 4 + 1] * rs);
    o.z = f2bfu(x[i * 4 + 2] * rs); o.w = f2bfu(x[i * 4 + 3] * rs);
    ptr[lane + i * 64] = o;
  }
}

// out[b][s][d] = sum_t P[b][s][t] * vT[b][d][t]; f32 out. grid (bn=4,bm=16,z=8).
__global__ __launch_bounds__(256, 4)
void pv_kernel(const bf16* __restrict__ P, const bf16* __restrict__ vT,
               float* __restrict__ out)
{
  __shared__ __align__(16) short As[64 * 64];
  __shared__ __align__(16) short Bs[128 * 64];
  const int z = blockIdx.z;
  const int bn = blockIdx.x, bm = blockIdx.y;
  f32x4 acc[8];
  gemm_core<64, 1024, 1024, 1024>(P + (size_t)z * SS * SS, vT + (size_t)z * DKK * SS,
                                  bm, bn, As, Bs, acc);

  const int lane = threadIdx.x & 63;
  const int wave = threadIdx.x >> 6;
  const int waveM = wave >> 1, waveN = wave & 1;
  const int l16 = lane & 15, quad = lane >> 4;
  const int row0 = bm * 64 + waveM * 32;
  const int col0 = bn * 128 + waveN * 64;
  float* C = out + (size_t)z * SS * DKK;
  #pragma unroll
  for (int ni = 0; ni < 4; ++ni) {
    const int col = col0 + ni * 16 + l16;
    #pragma unroll
    for (int mi = 0; mi < 2; ++mi)
      #pragma unroll
      for (int r = 0; r < 4; ++r) {
        const int row = row0 + mi * 16 + quad * 4 + r;
        C[(size_t)row * DKK + col] = acc[mi * 4 + ni][r];
      }
  }
}

extern "C" void kernel_launch(void* const* d_in, const int* in_sizes, int n_in,
                              void* d_out, int out_size, void* d_ws, size_t ws_size,
                              hipStream_t stream)
{
  char* ws = (char*)d_ws;
  bf16* W0  = (bf16*)(ws + WS_W(0));
  bf16* q   = (bf16*)(ws + WS_Q);
  bf16* kk  = (bf16*)(ws + WS_K);
  bf16* vT  = (bf16*)(ws + WS_VT);
  bf16* lgB = (bf16*)(ws + WS_LG);

  const float qscale = 0.044194173824159216f;  // 512^-0.5

  dim3 blk(256, 1, 1);
  // d_in order: qin,kin,vin,Wq,bq,Wk,bk,Wv,bv (all f32)
  hipLaunchKernelGGL(convert_w, dim3(768), blk, 0, stream,
                     (const float*)d_in[3], (const float*)d_in[5],
                     (const float*)d_in[7], ws);
  hipLaunchKernelGGL(proj_kernel, dim3(4, 64, 3), blk, 0, stream,
                     (const float*)d_in[0], (const float*)d_in[1],
                     (const float*)d_in[2], W0,
                     (const float*)d_in[4], (const float*)d_in[6],
                     (const float*)d_in[8], q, kk, vT, qscale);
  hipLaunchKernelGGL(scores_kernel, dim3(8, 16, 8), blk, 0, stream, q, kk, lgB);
  hipLaunchKernelGGL(softmax_kernel, dim3(2048, 1, 1), blk, 0, stream,
                     (unsigned short*)lgB);
  hipLaunchKernelGGL(pv_kernel, dim3(4, 16, 8), blk, 0, stream,
                     lgB, vT, (float*)d_out);
}

// Round 5
// 224.887 us; speedup vs baseline: 1.0247x; 1.0247x over previous
//
#include <hip/hip_runtime.h>
#include <hip/hip_bf16.h>

// Problem: B=8, S=1024, EMBED=1024, DK=DV=512, M=64. Inputs/outputs f32.
// Identity: landmark selection is a segment permutation P of k, so
// kernel_1 = K3 P^T, pinv(kernel_2) = P pinv(K3), and
// out = K3 K3+ K3 v = K3 v == softmax(q k^T) v  (standard attention).
#define SS   1024
#define DKK  512

typedef __hip_bfloat16 bf16;
typedef __attribute__((ext_vector_type(8))) short s16x8;            // 8 x bf16
typedef __attribute__((ext_vector_type(8))) unsigned short u16x8;
typedef __attribute__((ext_vector_type(4))) float f32x4;

// ---- ws layout (byte offsets), 76 MiB ----
// W(z) bf16 1 MiB at 48+z MiB; q 52 MiB; k 60 MiB; vT 68 MiB; logits 16 MiB at 0.
#define WS_W(z)  ((48ull << 20) + ((size_t)(z) << 20))
#define WS_Q     (52ull << 20)
#define WS_K     (60ull << 20)
#define WS_VT    (68ull << 20)
#define WS_LG    (0ull)

__device__ __forceinline__ void async_ld16(const void* g, void* s) {
  __builtin_amdgcn_global_load_lds(
      (const __attribute__((address_space(1))) void*)g,
      (__attribute__((address_space(3))) void*)s, 16, 0, 0);
}

__device__ __forceinline__ unsigned short f2bfu(float f) {
  return __builtin_bit_cast(unsigned short, __float2bfloat16(f));
}
__device__ __forceinline__ float bfu2f(unsigned short u) {
  unsigned int i = ((unsigned int)u) << 16;
  return __builtin_bit_cast(float, i);
}

// Convert the 3 weight tensors (512K elems each) f32 -> bf16 into ws.
__global__ __launch_bounds__(256)
void convert_w(const float* __restrict__ w0, const float* __restrict__ w1,
               const float* __restrict__ w2, char* __restrict__ ws)
{
  const int bx = blockIdx.x;
  const int z = bx >> 8, local = bx & 255;
  const float* src = (z == 0) ? w0 : (z == 1) ? w1 : w2;
  unsigned short* dst = (unsigned short*)(ws + WS_W(z));
  const int i = local * 2048 + threadIdx.x * 8;
  const float4* s = (const float4*)(src + i);
  float4 a = s[0], b = s[1];
  ushort4 o0, o1;
  o0.x = f2bfu(a.x); o0.y = f2bfu(a.y); o0.z = f2bfu(a.z); o0.w = f2bfu(a.w);
  o1.x = f2bfu(b.x); o1.y = f2bfu(b.y); o1.z = f2bfu(b.z); o1.w = f2bfu(b.w);
  ((ushort4*)(dst + i))[0] = o0;
  ((ushort4*)(dst + i))[1] = o1;
}

// ---------- bf16 x bf16 core (scores / pv) ----------
// C[BM x 128] = A[BM x K] * B[128 x K]^T, both K-contiguous bf16.
// LDS via global_load_lds w=16; LDS[row][slot] holds chunk (slot ^ (row&7)).
template<int BM, int K, int LDA, int LDB>
__device__ __forceinline__ void gemm_core(const bf16* __restrict__ A,
                                          const bf16* __restrict__ Bw,
                                          int bm, int bn,
                                          short* As, short* Bs, f32x4* acc)
{
  constexpr int MI = BM / 32;
  constexpr int AR = BM / 4;
  const int tid  = threadIdx.x;
  const int lane = tid & 63;
  const int wave = tid >> 6;
  const int l8   = lane >> 3;
  const int kch  = ((lane & 7) ^ l8) * 8;
  const bf16* ag = A  + (size_t)(bm * BM + wave * AR + l8) * LDA + kch;
  const bf16* bg = Bw + (size_t)(bn * 128 + wave * 32 + l8) * LDB + kch;
  short* AsW = As + wave * AR * 64;
  short* BsW = Bs + wave * 32 * 64;
  const int waveM = wave >> 1, waveN = wave & 1;
  const int l16  = lane & 15;
  const int quad = lane >> 4;
  const int xr   = l16 & 7;

  #pragma unroll
  for (int t = 0; t < MI * 4; ++t)
    #pragma unroll
    for (int r = 0; r < 4; ++r) acc[t][r] = 0.0f;

  for (int kt = 0; kt < K / 64; ++kt) {
    #pragma unroll
    for (int j = 0; j < AR / 8; ++j) async_ld16(ag + (size_t)j * 8 * LDA, AsW + j * 8 * 64);
    #pragma unroll
    for (int j = 0; j < 4; ++j)      async_ld16(bg + (size_t)j * 8 * LDB, BsW + j * 8 * 64);
    ag += 64; bg += 64;
    __syncthreads();
    #pragma unroll
    for (int ks = 0; ks < 2; ++ks) {
      s16x8 af[MI], bfv[4];
      #pragma unroll
      for (int mi = 0; mi < MI; ++mi) {
        const int row  = waveM * (BM / 2) + mi * 16 + l16;
        const int slot = (ks * 4 + quad) ^ xr;
        af[mi] = *(const s16x8*)&As[row * 64 + slot * 8];
      }
      #pragma unroll
      for (int ni = 0; ni < 4; ++ni) {
        const int row  = waveN * 64 + ni * 16 + l16;
        const int slot = (ks * 4 + quad) ^ xr;
        bfv[ni] = *(const s16x8*)&Bs[row * 64 + slot * 8];
      }
      #pragma unroll
      for (int mi = 0; mi < MI; ++mi)
        #pragma unroll
        for (int ni = 0; ni < 4; ++ni)
          acc[mi * 4 + ni] = __builtin_amdgcn_mfma_f32_16x16x32_bf16(
              af[mi], bfv[ni], acc[mi * 4 + ni], 0, 0, 0);
    }
    __syncthreads();
  }
}

// ---------- f32-A x bf16-B core for proj: BM=128, BN=256 ----------
// A f32 staged via reg round-trip + inline cvt into swizzled LDS;
// B bf16 on the async global_load_lds path. Wave tile 64x128:
// MI=4, NI=8, acc = 32 f32x4.
template<int K, int LDA, int LDB>
__device__ __forceinline__ void gemm_core_f32a(const float* __restrict__ A,
                                               const bf16* __restrict__ Bw,
                                               int bm, int bn,
                                               short* As, short* Bs, f32x4* acc)
{
  const int tid  = threadIdx.x;
  const int lane = tid & 63;
  const int wave = tid >> 6;
  const int l8   = lane >> 3;
  const int kch  = ((lane & 7) ^ l8) * 8;
  // B: 256 rows, wave stages rows wave*64 + j*8 + l8
  const bf16* bg = Bw + (size_t)(bn * 256 + wave * 64 + l8) * LDB + kch;
  short* BsW = Bs + wave * 64 * 64;
  // A: pass p covers rows p*32 + (tid>>3); 8 lanes x 32B contiguous per row.
  const int arow = tid >> 3;
  const int ag8  = tid & 7;
  const int slotA = (ag8 ^ (arow & 7)) * 8;
  const float* ag = A + (size_t)(bm * 128 + arow) * LDA + ag8 * 8;
  const int waveM = wave >> 1, waveN = wave & 1;
  const int l16  = lane & 15;
  const int quad = lane >> 4;
  const int xr   = l16 & 7;

  #pragma unroll
  for (int t = 0; t < 32; ++t)
    #pragma unroll
    for (int r = 0; r < 4; ++r) acc[t][r] = 0.0f;

  for (int kt = 0; kt < K / 64; ++kt) {
    #pragma unroll
    for (int j = 0; j < 8; ++j) async_ld16(bg + (size_t)j * 8 * LDB, BsW + j * 8 * 64);
    bg += 64;
    #pragma unroll
    for (int p = 0; p < 4; ++p) {
      const float4* s = (const float4*)(ag + (size_t)p * 32 * LDA);
      float4 a = s[0], b = s[1];
      u16x8 v;
      v[0] = f2bfu(a.x); v[1] = f2bfu(a.y); v[2] = f2bfu(a.z); v[3] = f2bfu(a.w);
      v[4] = f2bfu(b.x); v[5] = f2bfu(b.y); v[6] = f2bfu(b.z); v[7] = f2bfu(b.w);
      *(u16x8*)&As[(p * 32 + arow) * 64 + slotA] = v;
    }
    ag += 64;
    __syncthreads();
    #pragma unroll
    for (int ks = 0; ks < 2; ++ks) {
      s16x8 af[4], bfv[8];
      #pragma unroll
      for (int mi = 0; mi < 4; ++mi) {
        const int row  = waveM * 64 + mi * 16 + l16;
        const int slot = (ks * 4 + quad) ^ xr;
        af[mi] = *(const s16x8*)&As[row * 64 + slot * 8];
      }
      #pragma unroll
      for (int ni = 0; ni < 8; ++ni) {
        const int row  = waveN * 128 + ni * 16 + l16;
        const int slot = (ks * 4 + quad) ^ xr;
        bfv[ni] = *(const s16x8*)&Bs[row * 64 + slot * 8];
      }
      #pragma unroll
      for (int mi = 0; mi < 4; ++mi)
        #pragma unroll
        for (int ni = 0; ni < 8; ++ni)
          acc[mi * 8 + ni] = __builtin_amdgcn_mfma_f32_16x16x32_bf16(
              af[mi], bfv[ni], acc[mi * 8 + ni], 0, 0, 0);
    }
    __syncthreads();
  }
}

// z=0: q = (Xq Wq^T + bq) * 512^-0.5 ; z=1: k = Xk Wk^T + bk ;
// z=2: vT[b][d][s] = (Xv Wv^T + bv)^T  (so PV is also a BT-GEMM)
// Flat 384-block grid; decode so the two bn-siblings of each (bm,z) panel
// have linear ids differing by 8 -> same XCD (id%8) -> A panel shared in L2.
__global__ __launch_bounds__(256, 2)
void proj_kernel(const float* __restrict__ Xq, const float* __restrict__ Xk,
                 const float* __restrict__ Xv, const bf16* __restrict__ W0,
                 const float* __restrict__ bq, const float* __restrict__ bk,
                 const float* __restrict__ bv,
                 bf16* __restrict__ qo, bf16* __restrict__ ko,
                 bf16* __restrict__ vT, float qscale)
{
  __shared__ __align__(16) short As[128 * 64];
  __shared__ __align__(16) short Bs[256 * 64];
  const int id   = blockIdx.x;
  const int xcd  = id & 7;
  const int s    = id >> 3;            // 0..47
  const int bn   = s & 1;
  const int pair = (s >> 1) * 8 + xcd; // 0..191 unique
  const int bm   = pair & 63;
  const int z    = pair >> 6;          // 0..2
  const float* A  = (z == 0) ? Xq : (z == 1) ? Xk : Xv;
  const bf16*  Bw = W0 + ((size_t)z << 19);
  const float* bias = (z == 0) ? bq : (z == 1) ? bk : bv;
  f32x4 acc[32];
  gemm_core_f32a<1024, 1024, 1024>(A, Bw, bm, bn, As, Bs, acc);

  const int lane = threadIdx.x & 63;
  const int wave = threadIdx.x >> 6;
  const int waveM = wave >> 1, waveN = wave & 1;
  const int l16 = lane & 15, quad = lane >> 4;
  const int row0 = bm * 128 + waveM * 64;
  const int col0 = bn * 256 + waveN * 128;
  const float sc = (z == 0) ? qscale : 1.0f;
  bf16* C = (z == 0) ? qo : ko;
  #pragma unroll
  for (int ni = 0; ni < 8; ++ni) {
    const int col = col0 + ni * 16 + l16;
    const float bb = bias[col];
    #pragma unroll
    for (int mi = 0; mi < 4; ++mi)
      #pragma unroll
      for (int r = 0; r < 4; ++r) {
        const int row = row0 + mi * 16 + quad * 4 + r;
        const float v = acc[mi * 8 + ni][r] + bb;
        if (z == 2)
          vT[((size_t)(row >> 10) * DKK + col) * SS + (row & (SS - 1))] =
              __float2bfloat16(v);
        else
          C[(size_t)row * DKK + col] = __float2bfloat16(v * sc);
      }
  }
}

// logits[b][s][t] = q[b][s].k[b][t]; BM=64 tiles. grid (bn=8, bm=16, z=8).
__global__ __launch_bounds__(256, 4)
void scores_kernel(const bf16* __restrict__ q, const bf16* __restrict__ k,
                   bf16* __restrict__ lgB)
{
  __shared__ __align__(16) short As[64 * 64];
  __shared__ __align__(16) short Bs[128 * 64];
  const int z = blockIdx.z;
  const int bn = blockIdx.x, bm = blockIdx.y;
  f32x4 acc[8];
  gemm_core<64, 512, 512, 512>(q + (size_t)z * SS * DKK, k + (size_t)z * SS * DKK,
                               bm, bn, As, Bs, acc);

  const int lane = threadIdx.x & 63;
  const int wave = threadIdx.x >> 6;
  const int waveM = wave >> 1, waveN = wave & 1;
  const int l16 = lane & 15, quad = lane >> 4;
  const int row0 = bm * 64 + waveM * 32;
  const int col0 = bn * 128 + waveN * 64;
  bf16* C = lgB + (size_t)z * SS * SS;
  #pragma unroll
  for (int ni = 0; ni < 4; ++ni) {
    const int col = col0 + ni * 16 + l16;
    #pragma unroll
    for (int mi = 0; mi < 2; ++mi)
      #pragma unroll
      for (int r = 0; r < 4; ++r) {
        const int row = row0 + mi * 16 + quad * 4 + r;
        C[(size_t)row * SS + col] = __float2bfloat16(acc[mi * 4 + ni][r]);
      }
  }
}

// In-place row softmax; one wave per 1024-wide bf16 row.
__global__ __launch_bounds__(256)
void softmax_kernel(unsigned short* __restrict__ Pm)
{
  const int lane = threadIdx.x & 63;
  const int wv   = threadIdx.x >> 6;
  const size_t row = (size_t)blockIdx.x * 4 + wv;
  ushort4* ptr = (ushort4*)(Pm + row * SS);
  ushort4 u[4];
  float x[16];
  #pragma unroll
  for (int i = 0; i < 4; ++i) u[i] = ptr[lane + i * 64];
  #pragma unroll
  for (int i = 0; i < 4; ++i) {
    x[i * 4 + 0] = bfu2f(u[i].x); x[i * 4 + 1] = bfu2f(u[i].y);
    x[i * 4 + 2] = bfu2f(u[i].z); x[i * 4 + 3] = bfu2f(u[i].w);
  }
  float m = x[0];
  #pragma unroll
  for (int i = 1; i < 16; ++i) m = fmaxf(m, x[i]);
  #pragma unroll
  for (int off = 32; off > 0; off >>= 1) m = fmaxf(m, __shfl_xor(m, off));
  float s = 0.f;
  #pragma unroll
  for (int i = 0; i < 16; ++i) { x[i] = __expf(x[i] - m); s += x[i]; }
  #pragma unroll
  for (int off = 32; off > 0; off >>= 1) s += __shfl_xor(s, off);
  const float rs = 1.0f / s;
  #pragma unroll
  for (int i = 0; i < 4; ++i) {
    ushort4 o;
    o.x = f2bfu(x[i * 4 + 0] * rs); o.y = f2bfu(x[i * 4 + 1] * rs);
    o.z = f2bfu(x[i * 4 + 2] * rs); o.w = f2bfu(x[i * 4 + 3] * rs);
    ptr[lane + i * 64] = o;
  }
}

// out[b][s][d] = sum_t P[b][s][t] * vT[b][d][t]; f32 out. grid (bn=4,bm=16,z=8).
__global__ __launch_bounds__(256, 4)
void pv_kernel(const bf16* __restrict__ P, const bf16* __restrict__ vT,
               float* __restrict__ out)
{
  __shared__ __align__(16) short As[64 * 64];
  __shared__ __align__(16) short Bs[128 * 64];
  const int z = blockIdx.z;
  const int bn = blockIdx.x, bm = blockIdx.y;
  f32x4 acc[8];
  gemm_core<64, 1024, 1024, 1024>(P + (size_t)z * SS * SS, vT + (size_t)z * DKK * SS,
                                  bm, bn, As, Bs, acc);

  const int lane = threadIdx.x & 63;
  const int wave = threadIdx.x >> 6;
  const int waveM = wave >> 1, waveN = wave & 1;
  const int l16 = lane & 15, quad = lane >> 4;
  const int row0 = bm * 64 + waveM * 32;
  const int col0 = bn * 128 + waveN * 64;
  float* C = out + (size_t)z * SS * DKK;
  #pragma unroll
  for (int ni = 0; ni < 4; ++ni) {
    const int col = col0 + ni * 16 + l16;
    #pragma unroll
    for (int mi = 0; mi < 2; ++mi)
      #pragma unroll
      for (int r = 0; r < 4; ++r) {
        const int row = row0 + mi * 16 + quad * 4 + r;
        C[(size_t)row * DKK + col] = acc[mi * 4 + ni][r];
      }
  }
}

extern "C" void kernel_launch(void* const* d_in, const int* in_sizes, int n_in,
                              void* d_out, int out_size, void* d_ws, size_t ws_size,
                              hipStream_t stream)
{
  char* ws = (char*)d_ws;
  bf16* W0  = (bf16*)(ws + WS_W(0));
  bf16* q   = (bf16*)(ws + WS_Q);
  bf16* kk  = (bf16*)(ws + WS_K);
  bf16* vT  = (bf16*)(ws + WS_VT);
  bf16* lgB = (bf16*)(ws + WS_LG);

  const float qscale = 0.044194173824159216f;  // 512^-0.5

  dim3 blk(256, 1, 1);
  // d_in order: qin,kin,vin,Wq,bq,Wk,bk,Wv,bv (all f32)
  hipLaunchKernelGGL(convert_w, dim3(768), blk, 0, stream,
                     (const float*)d_in[3], (const float*)d_in[5],
                     (const float*)d_in[7], ws);
  hipLaunchKernelGGL(proj_kernel, dim3(384, 1, 1), blk, 0, stream,
                     (const float*)d_in[0], (const float*)d_in[1],
                     (const float*)d_in[2], W0,
                     (const float*)d_in[4], (const float*)d_in[6],
                     (const float*)d_in[8], q, kk, vT, qscale);
  hipLaunchKernelGGL(scores_kernel, dim3(8, 16, 8), blk, 0, stream, q, kk, lgB);
  hipLaunchKernelGGL(softmax_kernel, dim3(2048, 1, 1), blk, 0, stream,
                     (unsigned short*)lgB);
  hipLaunchKernelGGL(pv_kernel, dim3(4, 16, 8), blk, 0, stream,
                     lgB, vT, (float*)d_out);
}

// Round 6
// 220.667 us; speedup vs baseline: 1.0443x; 1.0191x over previous
//
#include <hip/hip_runtime.h>
#include <hip/hip_bf16.h>

// Problem: B=8, S=1024, EMBED=1024, DK=DV=512, M=64. Inputs/outputs f32.
// Identity: landmark selection is a segment permutation P of k, so
// kernel_1 = K3 P^T, pinv(kernel_2) = P pinv(K3), and
// out = K3 K3+ K3 v = K3 v == softmax(q k^T) v  (standard attention).
#define SS   1024
#define DKK  512

typedef __hip_bfloat16 bf16;
typedef __attribute__((ext_vector_type(8))) short s16x8;            // 8 x bf16
typedef __attribute__((ext_vector_type(8))) unsigned short u16x8;
typedef __attribute__((ext_vector_type(4))) float f32x4;

// ---- ws layout (byte offsets), 76 MiB ----
// logits 16 MiB at 0; W(z) bf16 1 MiB at 48+z MiB; stats 1 MiB at 51 MiB;
// q 52 MiB; k 60 MiB; vT 68 MiB.
#define WS_W(z)  ((48ull << 20) + ((size_t)(z) << 20))
#define WS_ST    (51ull << 20)
#define WS_Q     (52ull << 20)
#define WS_K     (60ull << 20)
#define WS_VT    (68ull << 20)
#define WS_LG    (0ull)

__device__ __forceinline__ void async_ld16(const void* g, void* s) {
  __builtin_amdgcn_global_load_lds(
      (const __attribute__((address_space(1))) void*)g,
      (__attribute__((address_space(3))) void*)s, 16, 0, 0);
}

__device__ __forceinline__ unsigned short f2bfu(float f) {
  return __builtin_bit_cast(unsigned short, __float2bfloat16(f));
}
__device__ __forceinline__ float bfu2f(unsigned short u) {
  unsigned int i = ((unsigned int)u) << 16;
  return __builtin_bit_cast(float, i);
}

// Convert the 3 weight tensors (512K elems each) f32 -> bf16 into ws.
__global__ __launch_bounds__(256)
void convert_w(const float* __restrict__ w0, const float* __restrict__ w1,
               const float* __restrict__ w2, char* __restrict__ ws)
{
  const int bx = blockIdx.x;
  const int z = bx >> 8, local = bx & 255;
  const float* src = (z == 0) ? w0 : (z == 1) ? w1 : w2;
  unsigned short* dst = (unsigned short*)(ws + WS_W(z));
  const int i = local * 2048 + threadIdx.x * 8;
  const float4* s = (const float4*)(src + i);
  float4 a = s[0], b = s[1];
  ushort4 o0, o1;
  o0.x = f2bfu(a.x); o0.y = f2bfu(a.y); o0.z = f2bfu(a.z); o0.w = f2bfu(a.w);
  o1.x = f2bfu(b.x); o1.y = f2bfu(b.y); o1.z = f2bfu(b.z); o1.w = f2bfu(b.w);
  ((ushort4*)(dst + i))[0] = o0;
  ((ushort4*)(dst + i))[1] = o1;
}

// ---------- bf16 x bf16 core (scores) ----------
// C[BM x 128] = A[BM x K] * B[128 x K]^T, both K-contiguous bf16.
// LDS via global_load_lds w=16; LDS[row][slot] holds chunk (slot ^ (row&7)).
template<int BM, int K, int LDA, int LDB>
__device__ __forceinline__ void gemm_core(const bf16* __restrict__ A,
                                          const bf16* __restrict__ Bw,
                                          int bm, int bn,
                                          short* As, short* Bs, f32x4* acc)
{
  constexpr int MI = BM / 32;
  constexpr int AR = BM / 4;
  const int tid  = threadIdx.x;
  const int lane = tid & 63;
  const int wave = tid >> 6;
  const int l8   = lane >> 3;
  const int kch  = ((lane & 7) ^ l8) * 8;
  const bf16* ag = A  + (size_t)(bm * BM + wave * AR + l8) * LDA + kch;
  const bf16* bg = Bw + (size_t)(bn * 128 + wave * 32 + l8) * LDB + kch;
  short* AsW = As + wave * AR * 64;
  short* BsW = Bs + wave * 32 * 64;
  const int waveM = wave >> 1, waveN = wave & 1;
  const int l16  = lane & 15;
  const int quad = lane >> 4;
  const int xr   = l16 & 7;

  #pragma unroll
  for (int t = 0; t < MI * 4; ++t)
    #pragma unroll
    for (int r = 0; r < 4; ++r) acc[t][r] = 0.0f;

  for (int kt = 0; kt < K / 64; ++kt) {
    #pragma unroll
    for (int j = 0; j < AR / 8; ++j) async_ld16(ag + (size_t)j * 8 * LDA, AsW + j * 8 * 64);
    #pragma unroll
    for (int j = 0; j < 4; ++j)      async_ld16(bg + (size_t)j * 8 * LDB, BsW + j * 8 * 64);
    ag += 64; bg += 64;
    __syncthreads();
    #pragma unroll
    for (int ks = 0; ks < 2; ++ks) {
      s16x8 af[MI], bfv[4];
      #pragma unroll
      for (int mi = 0; mi < MI; ++mi) {
        const int row  = waveM * (BM / 2) + mi * 16 + l16;
        const int slot = (ks * 4 + quad) ^ xr;
        af[mi] = *(const s16x8*)&As[row * 64 + slot * 8];
      }
      #pragma unroll
      for (int ni = 0; ni < 4; ++ni) {
        const int row  = waveN * 64 + ni * 16 + l16;
        const int slot = (ks * 4 + quad) ^ xr;
        bfv[ni] = *(const s16x8*)&Bs[row * 64 + slot * 8];
      }
      #pragma unroll
      for (int mi = 0; mi < MI; ++mi)
        #pragma unroll
        for (int ni = 0; ni < 4; ++ni)
          acc[mi * 4 + ni] = __builtin_amdgcn_mfma_f32_16x16x32_bf16(
              af[mi], bfv[ni], acc[mi * 4 + ni], 0, 0, 0);
    }
    __syncthreads();
  }
}

// ---------- f32-A x bf16-B core for proj: BM=64, BN=256 ----------
// A f32 staged via reg round-trip + inline cvt into swizzled LDS;
// B bf16 on the async global_load_lds path. Wave tile 32x128.
template<int K, int LDA, int LDB>
__device__ __forceinline__ void gemm_core_f32a(const float* __restrict__ A,
                                               const bf16* __restrict__ Bw,
                                               int bm, int bn,
                                               short* As, short* Bs, f32x4* acc)
{
  const int tid  = threadIdx.x;
  const int lane = tid & 63;
  const int wave = tid >> 6;
  const int l8   = lane >> 3;
  const int kch  = ((lane & 7) ^ l8) * 8;
  const bf16* bg = Bw + (size_t)(bn * 256 + wave * 64 + l8) * LDB + kch;
  short* BsW = Bs + wave * 64 * 64;
  const int arow = tid >> 3;
  const int ag8  = tid & 7;
  const int slotA = (ag8 ^ (arow & 7)) * 8;
  const float* ag = A + (size_t)(bm * 64 + arow) * LDA + ag8 * 8;
  const int waveM = wave >> 1, waveN = wave & 1;
  const int l16  = lane & 15;
  const int quad = lane >> 4;
  const int xr   = l16 & 7;

  #pragma unroll
  for (int t = 0; t < 16; ++t)
    #pragma unroll
    for (int r = 0; r < 4; ++r) acc[t][r] = 0.0f;

  for (int kt = 0; kt < K / 64; ++kt) {
    #pragma unroll
    for (int j = 0; j < 8; ++j) async_ld16(bg + (size_t)j * 8 * LDB, BsW + j * 8 * 64);
    bg += 64;
    #pragma unroll
    for (int p = 0; p < 2; ++p) {
      const float4* s = (const float4*)(ag + (size_t)p * 32 * LDA);
      float4 a = s[0], b = s[1];
      u16x8 v;
      v[0] = f2bfu(a.x); v[1] = f2bfu(a.y); v[2] = f2bfu(a.z); v[3] = f2bfu(a.w);
      v[4] = f2bfu(b.x); v[5] = f2bfu(b.y); v[6] = f2bfu(b.z); v[7] = f2bfu(b.w);
      *(u16x8*)&As[(p * 32 + arow) * 64 + slotA] = v;
    }
    ag += 64;
    __syncthreads();
    #pragma unroll
    for (int ks = 0; ks < 2; ++ks) {
      s16x8 af[2], bfv[8];
      #pragma unroll
      for (int mi = 0; mi < 2; ++mi) {
        const int row  = waveM * 32 + mi * 16 + l16;
        const int slot = (ks * 4 + quad) ^ xr;
        af[mi] = *(const s16x8*)&As[row * 64 + slot * 8];
      }
      #pragma unroll
      for (int ni = 0; ni < 8; ++ni) {
        const int row  = waveN * 128 + ni * 16 + l16;
        const int slot = (ks * 4 + quad) ^ xr;
        bfv[ni] = *(const s16x8*)&Bs[row * 64 + slot * 8];
      }
      #pragma unroll
      for (int mi = 0; mi < 2; ++mi)
        #pragma unroll
        for (int ni = 0; ni < 8; ++ni)
          acc[mi * 8 + ni] = __builtin_amdgcn_mfma_f32_16x16x32_bf16(
              af[mi], bfv[ni], acc[mi * 8 + ni], 0, 0, 0);
    }
    __syncthreads();
  }
}

// z=0: q = (Xq Wq^T + bq) * 512^-0.5 ; z=1: k = Xk Wk^T + bk ;
// z=2: vT[b][d][s] = (Xv Wv^T + bv)^T.
// Flat 768-block grid; the two bn-siblings of each (bm,z) panel get linear
// ids differing by 8 -> same XCD -> A panel shared in that XCD's L2.
__global__ __launch_bounds__(256, 3)
void proj_kernel(const float* __restrict__ Xq, const float* __restrict__ Xk,
                 const float* __restrict__ Xv, const bf16* __restrict__ W0,
                 const float* __restrict__ bq, const float* __restrict__ bk,
                 const float* __restrict__ bv,
                 bf16* __restrict__ qo, bf16* __restrict__ ko,
                 bf16* __restrict__ vT, float qscale)
{
  __shared__ __align__(16) short As[64 * 64];
  __shared__ __align__(16) short Bs[256 * 64];
  const int id   = blockIdx.x;
  const int xcd  = id & 7;
  const int s    = id >> 3;            // 0..95
  const int bn   = s & 1;
  const int pair = (s >> 1) * 8 + xcd; // 0..383 unique
  const int bm   = pair & 127;
  const int z    = pair >> 7;          // 0..2
  const float* A  = (z == 0) ? Xq : (z == 1) ? Xk : Xv;
  const bf16*  Bw = W0 + ((size_t)z << 19);
  const float* bias = (z == 0) ? bq : (z == 1) ? bk : bv;
  f32x4 acc[16];
  gemm_core_f32a<1024, 1024, 1024>(A, Bw, bm, bn, As, Bs, acc);

  const int lane = threadIdx.x & 63;
  const int wave = threadIdx.x >> 6;
  const int waveM = wave >> 1, waveN = wave & 1;
  const int l16 = lane & 15, quad = lane >> 4;
  const int row0 = bm * 64 + waveM * 32;
  const int col0 = bn * 256 + waveN * 128;
  const float sc = (z == 0) ? qscale : 1.0f;
  bf16* C = (z == 0) ? qo : ko;
  #pragma unroll
  for (int ni = 0; ni < 8; ++ni) {
    const int col = col0 + ni * 16 + l16;
    const float bb = bias[col];
    #pragma unroll
    for (int mi = 0; mi < 2; ++mi)
      #pragma unroll
      for (int r = 0; r < 4; ++r) {
        const int row = row0 + mi * 16 + quad * 4 + r;
        const float v = acc[mi * 8 + ni][r] + bb;
        if (z == 2)
          vT[((size_t)(row >> 10) * DKK + col) * SS + (row & (SS - 1))] =
              __float2bfloat16(v);
        else
          C[(size_t)row * DKK + col] = __float2bfloat16(v * sc);
      }
  }
}

// logits[b][s][t] = q[b][s].k[b][t]; BM=64 tiles. grid (bn=8, bm=16, z=8).
// Epilogue also writes per-(row, 64-col-chunk) softmax stats (max, expsum)
// computed on the bf16-ROUNDED logits (bit-consistent with what pv re-reads).
__global__ __launch_bounds__(256, 4)
void scores_kernel(const bf16* __restrict__ q, const bf16* __restrict__ k,
                   bf16* __restrict__ lgB, float* __restrict__ stats)
{
  __shared__ __align__(16) short As[64 * 64];
  __shared__ __align__(16) short Bs[128 * 64];
  const int z = blockIdx.z;
  const int bn = blockIdx.x, bm = blockIdx.y;
  f32x4 acc[8];
  gemm_core<64, 512, 512, 512>(q + (size_t)z * SS * DKK, k + (size_t)z * SS * DKK,
                               bm, bn, As, Bs, acc);

  const int lane = threadIdx.x & 63;
  const int wave = threadIdx.x >> 6;
  const int waveM = wave >> 1, waveN = wave & 1;
  const int l16 = lane & 15, quad = lane >> 4;
  const int row0 = bm * 64 + waveM * 32;
  const int col0 = bn * 128 + waveN * 64;
  bf16* C = lgB + (size_t)z * SS * SS;
  #pragma unroll
  for (int ni = 0; ni < 4; ++ni) {
    const int col = col0 + ni * 16 + l16;
    #pragma unroll
    for (int mi = 0; mi < 2; ++mi)
      #pragma unroll
      for (int r = 0; r < 4; ++r) {
        const int row = row0 + mi * 16 + quad * 4 + r;
        C[(size_t)row * SS + col] = __float2bfloat16(acc[mi * 4 + ni][r]);
      }
  }
  // stats over the 64-col slice this wave owns (16-lane groups share a row)
  const int chunk = bn * 2 + waveN;
  #pragma unroll
  for (int mi = 0; mi < 2; ++mi)
    #pragma unroll
    for (int r = 0; r < 4; ++r) {
      float xr4[4];
      float m = -1e30f;
      #pragma unroll
      for (int ni = 0; ni < 4; ++ni) {
        xr4[ni] = bfu2f(f2bfu(acc[mi * 4 + ni][r]));
        m = fmaxf(m, xr4[ni]);
      }
      #pragma unroll
      for (int msk = 1; msk < 16; msk <<= 1) m = fmaxf(m, __shfl_xor(m, msk));
      float e = 0.f;
      #pragma unroll
      for (int ni = 0; ni < 4; ++ni) e += __expf(xr4[ni] - m);
      #pragma unroll
      for (int msk = 1; msk < 16; msk <<= 1) e += __shfl_xor(e, msk);
      if (l16 == 0) {
        const int row = row0 + mi * 16 + quad * 4 + r;
        float2 mr; mr.x = m; mr.y = e;
        *(float2*)&stats[(((size_t)z * SS + row) * 16 + chunk) * 2] = mr;
      }
    }
}

// ---------- pv core: A = softmax'd logits (exp applied at staging) ----------
__device__ __forceinline__ void gemm_core_pv(const unsigned short* __restrict__ lg,
                                             const bf16* __restrict__ vT,
                                             int bm, int bn,
                                             const float* Ml, const float* Rl,
                                             short* As, short* Bs, f32x4* acc)
{
  const int tid  = threadIdx.x;
  const int lane = tid & 63;
  const int wave = tid >> 6;
  const int l8   = lane >> 3;
  const int kch  = ((lane & 7) ^ l8) * 8;
  const bf16* bg = vT + (size_t)(bn * 128 + wave * 32 + l8) * 1024 + kch;
  short* BsW = Bs + wave * 32 * 64;
  const int arow = tid >> 3;
  const int ag8  = tid & 7;
  const int slotA = (ag8 ^ (arow & 7)) * 8;
  const unsigned short* ag = lg + (size_t)(bm * 64 + arow) * 1024 + ag8 * 8;
  const int waveM = wave >> 1, waveN = wave & 1;
  const int l16  = lane & 15;
  const int quad = lane >> 4;
  const int xr   = l16 & 7;

  #pragma unroll
  for (int t = 0; t < 8; ++t)
    #pragma unroll
    for (int r = 0; r < 4; ++r) acc[t][r] = 0.0f;

  for (int kt = 0; kt < 16; ++kt) {
    #pragma unroll
    for (int j = 0; j < 4; ++j) async_ld16(bg + (size_t)j * 8 * 1024, BsW + j * 8 * 64);
    bg += 64;
    #pragma unroll
    for (int p = 0; p < 2; ++p) {
      const int rl = p * 32 + arow;
      u16x8 u = *(const u16x8*)(ag + (size_t)p * 32 * 1024);
      const float M = Ml[rl], R = Rl[rl];
      u16x8 v;
      #pragma unroll
      for (int j = 0; j < 8; ++j)
        v[j] = f2bfu(__expf(bfu2f((unsigned short)u[j]) - M) * R);
      *(u16x8*)&As[rl * 64 + slotA] = v;
    }
    ag += 64;
    __syncthreads();
    #pragma unroll
    for (int ks = 0; ks < 2; ++ks) {
      s16x8 af[2], bfv[4];
      #pragma unroll
      for (int mi = 0; mi < 2; ++mi) {
        const int row  = waveM * 32 + mi * 16 + l16;
        const int slot = (ks * 4 + quad) ^ xr;
        af[mi] = *(const s16x8*)&As[row * 64 + slot * 8];
      }
      #pragma unroll
      for (int ni = 0; ni < 4; ++ni) {
        const int row  = waveN * 64 + ni * 16 + l16;
        const int slot = (ks * 4 + quad) ^ xr;
        bfv[ni] = *(const s16x8*)&Bs[row * 64 + slot * 8];
      }
      #pragma unroll
      for (int mi = 0; mi < 2; ++mi)
        #pragma unroll
        for (int ni = 0; ni < 4; ++ni)
          acc[mi * 4 + ni] = __builtin_amdgcn_mfma_f32_16x16x32_bf16(
              af[mi], bfv[ni], acc[mi * 4 + ni], 0, 0, 0);
    }
    __syncthreads();
  }
}

// out[b][s][d] = softmax(logits)[b][s][:] . vT[b][d][:]; f32 out.
// grid (bn=4, bm=16, z=8).
__global__ __launch_bounds__(256, 4)
void pv_kernel(const unsigned short* __restrict__ lgB, const bf16* __restrict__ vT,
               const float* __restrict__ stats, float* __restrict__ out)
{
  __shared__ __align__(16) short As[64 * 64];
  __shared__ __align__(16) short Bs[128 * 64];
  __shared__ float Ml[64], Rl[64];
  const int z = blockIdx.z;
  const int bn = blockIdx.x, bm = blockIdx.y;
  const int tid = threadIdx.x;

  if (tid < 64) {
    const int row = bm * 64 + tid;
    const float* st = stats + ((size_t)z * SS + row) * 32;
    float mc[16], lc[16];
    float M = -1e30f;
    #pragma unroll
    for (int c = 0; c < 16; ++c) {
      mc[c] = st[c * 2]; lc[c] = st[c * 2 + 1];
      M = fmaxf(M, mc[c]);
    }
    float L = 0.f;
    #pragma unroll
    for (int c = 0; c < 16; ++c) L += __expf(mc[c] - M) * lc[c];
    Ml[tid] = M; Rl[tid] = 1.0f / L;
  }
  __syncthreads();

  f32x4 acc[8];
  gemm_core_pv(lgB + (size_t)z * SS * SS, vT + (size_t)z * DKK * SS,
               bm, bn, Ml, Rl, As, Bs, acc);

  const int lane = tid & 63;
  const int wave = tid >> 6;
  const int waveM = wave >> 1, waveN = wave & 1;
  const int l16 = lane & 15, quad = lane >> 4;
  const int row0 = bm * 64 + waveM * 32;
  const int col0 = bn * 128 + waveN * 64;
  float* C = out + (size_t)z * SS * DKK;
  #pragma unroll
  for (int ni = 0; ni < 4; ++ni) {
    const int col = col0 + ni * 16 + l16;
    #pragma unroll
    for (int mi = 0; mi < 2; ++mi)
      #pragma unroll
      for (int r = 0; r < 4; ++r) {
        const int row = row0 + mi * 16 + quad * 4 + r;
        C[(size_t)row * DKK + col] = acc[mi * 4 + ni][r];
      }
  }
}

extern "C" void kernel_launch(void* const* d_in, const int* in_sizes, int n_in,
                              void* d_out, int out_size, void* d_ws, size_t ws_size,
                              hipStream_t stream)
{
  char* ws = (char*)d_ws;
  bf16*  W0   = (bf16*)(ws + WS_W(0));
  float* stat = (float*)(ws + WS_ST);
  bf16*  q    = (bf16*)(ws + WS_Q);
  bf16*  kk   = (bf16*)(ws + WS_K);
  bf16*  vT   = (bf16*)(ws + WS_VT);
  bf16*  lgB  = (bf16*)(ws + WS_LG);

  const float qscale = 0.044194173824159216f;  // 512^-0.5

  dim3 blk(256, 1, 1);
  // d_in order: qin,kin,vin,Wq,bq,Wk,bk,Wv,bv (all f32)
  hipLaunchKernelGGL(convert_w, dim3(768), blk, 0, stream,
                     (const float*)d_in[3], (const float*)d_in[5],
                     (const float*)d_in[7], ws);
  hipLaunchKernelGGL(proj_kernel, dim3(768, 1, 1), blk, 0, stream,
                     (const float*)d_in[0], (const float*)d_in[1],
                     (const float*)d_in[2], W0,
                     (const float*)d_in[4], (const float*)d_in[6],
                     (const float*)d_in[8], q, kk, vT, qscale);
  hipLaunchKernelGGL(scores_kernel, dim3(8, 16, 8), blk, 0, stream,
                     q, kk, lgB, stat);
  hipLaunchKernelGGL(pv_kernel, dim3(4, 16, 8), blk, 0, stream,
                     (const unsigned short*)lgB, vT, stat, (float*)d_out);
}